// Round 2
// 197.401 us; speedup vs baseline: 1.1743x; 1.1743x over previous
//
#include <hip/hip_runtime.h>
#include <hip/hip_bf16.h>

// Problem constants (from reference)
#define N_NODES 100000
#define FEAT    256
#define HID     128
#define REL     2
#define BATCH   20000
#define KNEI    10

#define APAD    8            // pad shorts per LDS A row (breaks pow-2 stride)
#define AROW    (768 + APAD) // 776 shorts = 1552 B row stride

typedef short bf16x8 __attribute__((ext_vector_type(8)));
typedef float f32x4  __attribute__((ext_vector_type(4)));

__device__ __forceinline__ unsigned short f2bf(float x) {
    union { float f; unsigned u; } v; v.f = x;
    unsigned r = v.u + 0x7fffu + ((v.u >> 16) & 1u);   // RNE
    return (unsigned short)(r >> 16);
}

__device__ __forceinline__ ushort4 pack4(float a, float b, float c, float d) {
    ushort4 p; p.x = f2bf(a); p.y = f2bf(b); p.z = f2bf(c); p.w = f2bf(d);
    return p;
}

// Swizzled B index for logical (k, n):
//   kt=k>>5, j=k&7, hi=(k>>3)&3, lane=hi*16+(n&15), nt=n>>4
//   dest = ((kt*8+nt)*64 + lane)*8 + j
__device__ __forceinline__ size_t bsw_index(int k, int n) {
    int kt = k >> 5, j = k & 7, hi = (k >> 3) & 3;
    int lane = hi * 16 + (n & 15), nt = n >> 4;
    return ((size_t)(kt * 8 + nt) * 64 + lane) * 8 + j;
}

// ---------------------------------------------------------------------------
// prep_B: build collapsed weight into MFMA-swizzled bf16 layout.
// 8x more parallel than round-0 (272 blocks vs 34):
//   blocks 0..255  : one f-row per thread-half; 128-deep dot, fully unrolled
//                    so the compiler keeps many strided wd loads in flight.
//   blocks 256..271: straight copy of W_det rows 0..255 (coalesced reads).
// ---------------------------------------------------------------------------
__global__ __launch_bounds__(256) void prep_B(const float* __restrict__ W_stc,
                                              const float* __restrict__ W_det,
                                              unsigned short* __restrict__ Bsw) {
    const int blk = blockIdx.x;
    const int tid = threadIdx.x;
    if (blk < 256) {
        const int rel = blk >> 7;                      // 0..1
        const int f   = (blk & 127) * 2 + (tid >> 7);  // 0..255
        const int n   = tid & 127;
        const float* ws = W_stc + (size_t)(rel * FEAT + f) * HID;
        const float* wd = W_det + (size_t)(256 + rel * HID) * HID + n;  // column base
        float acc = 0.f;
        #pragma unroll
        for (int j = 0; j < HID; ++j) acc += ws[j] * wd[(size_t)j * HID];
        Bsw[bsw_index(256 + rel * 256 + f, n)] = f2bf(acc);
    } else {
        const int base = (blk - 256) * 2048;           // 16 blocks x 2048 elems
        #pragma unroll
        for (int i = 0; i < 8; ++i) {
            const int idx = base + i * 256 + tid;      // < 32768
            const int k = idx >> 7, n = idx & 127;
            Bsw[bsw_index(k, n)] = f2bf(W_det[idx]);
        }
    }
}

// ---------------------------------------------------------------------------
// fused: gather+mean into LDS A-tile (bf16), then MFMA GEMM + ReLU.
// One block (4 waves) per 16-row M-tile. 1250 blocks.
//   Phase 0: all 336 block indices staged into LDS via coalesced passes
//            (kills the per-row global index -> global row pointer chase).
//   Phase 1: wave w gathers batch elems m = w*4..w*4+3. All 21 row loads of
//            an element are issued into statically-indexed register arrays
//            before any accumulation -> ~21 loads in flight per wave.
//            launch_bounds(256,4): 128-VGPR cap holds the 84-reg load batch
//            with no scratch spill; 4 blocks/CU resident (same as baseline).
//   Phase 2: wave w computes n-tiles {w, w+4}: 24 kt x 2 MFMA from LDS A
//            fragments (ds_read_b128) and L2-resident swizzled B.
// ---------------------------------------------------------------------------
__global__ __launch_bounds__(256, 4) void fused(const int* __restrict__ nodes,
                                                const int* __restrict__ neigh_idx,
                                                const float* __restrict__ features,
                                                const unsigned short* __restrict__ Bsw,
                                                float* __restrict__ out) {
    __shared__ unsigned short As[16 * AROW];   // 24832 B
    __shared__ int idxs[336];                  // [0..15] self | [16..175] rel0 | [176..335] rel1

    const int blk  = blockIdx.x;               // m-tile id (0..1249)
    const int tid  = threadIdx.x;
    const int w    = tid >> 6;                 // wave 0..3
    const int lane = tid & 63;
    const float4* F4 = (const float4*)features;
    const float inv = 1.0f / (float)KNEI;

    // ---- Phase 0: stage indices into LDS (coalesced) ----
    {
        if (tid < 16)       idxs[tid] = nodes[blk * 16 + tid];
        else if (tid < 176) idxs[tid] = neigh_idx[blk * 160 + (tid - 16)];
        else                idxs[tid] = neigh_idx[BATCH * KNEI + blk * 160 + (tid - 176)];
        const int t2 = tid + 256;              // [256,336): rel1 tail
        if (t2 < 336)       idxs[t2] = neigh_idx[BATCH * KNEI + blk * 160 + (t2 - 176)];
    }
    __syncthreads();

    // ---- Phase 1: gather + mean, batched loads ----
    #pragma unroll
    for (int e = 0; e < 4; ++e) {
        const int m = w * 4 + e;               // row in tile
        const int* i0 = &idxs[16 + m * KNEI];
        const int* i1 = &idxs[176 + m * KNEI];

        float4 ta[11];                         // self + rel0 neighbors
        ta[0] = F4[(size_t)idxs[m] * 64 + lane];
        #pragma unroll
        for (int k = 0; k < KNEI; ++k)
            ta[1 + k] = F4[(size_t)i0[k] * 64 + lane];
        float4 tb[10];                         // rel1 neighbors
        #pragma unroll
        for (int k = 0; k < KNEI; ++k)
            tb[k] = F4[(size_t)i1[k] * 64 + lane];

        // serial accumulation in original k-order (preserves prior numerics)
        float4 s0 = ta[1];
        #pragma unroll
        for (int k = 1; k < KNEI; ++k) {
            s0.x += ta[1 + k].x; s0.y += ta[1 + k].y;
            s0.z += ta[1 + k].z; s0.w += ta[1 + k].w;
        }
        float4 s1 = tb[0];
        #pragma unroll
        for (int k = 1; k < KNEI; ++k) {
            s1.x += tb[k].x; s1.y += tb[k].y;
            s1.z += tb[k].z; s1.w += tb[k].w;
        }

        ushort4* row = (ushort4*)(As + m * AROW);
        row[lane]       = pack4(ta[0].x, ta[0].y, ta[0].z, ta[0].w);
        row[64 + lane]  = pack4(s0.x * inv, s0.y * inv, s0.z * inv, s0.w * inv);
        row[128 + lane] = pack4(s1.x * inv, s1.y * inv, s1.z * inv, s1.w * inv);
    }
    __syncthreads();

    // ---- Phase 2: GEMM + ReLU ----
    const int quad = lane >> 4;
    const int l16  = lane & 15;
    const unsigned short* a_base = As + l16 * AROW + quad * 8;

    f32x4 acc0 = (f32x4){0.f, 0.f, 0.f, 0.f};
    f32x4 acc1 = (f32x4){0.f, 0.f, 0.f, 0.f};
    const int nt0 = w, nt1 = w + 4;

    #pragma unroll
    for (int kt = 0; kt < 24; ++kt) {
        bf16x8 a = *(const bf16x8*)(a_base + kt * 32);
        const unsigned short* bk = Bsw + ((size_t)(kt * 8) * 64 + lane) * 8;
        bf16x8 b0 = *(const bf16x8*)(bk + (size_t)nt0 * 64 * 8);
        bf16x8 b1 = *(const bf16x8*)(bk + (size_t)nt1 * 64 * 8);
        acc0 = __builtin_amdgcn_mfma_f32_16x16x32_bf16(a, b0, acc0, 0, 0, 0);
        acc1 = __builtin_amdgcn_mfma_f32_16x16x32_bf16(a, b1, acc1, 0, 0, 0);
    }

    float* orow = out + (size_t)(blk * 16) * HID;
    #pragma unroll
    for (int r = 0; r < 4; ++r) {
        const int row = quad * 4 + r;
        float v0 = acc0[r];
        float v1 = acc1[r];
        orow[(size_t)row * HID + nt0 * 16 + l16] = v0 > 0.f ? v0 : 0.f;
        orow[(size_t)row * HID + nt1 * 16 + l16] = v1 > 0.f ? v1 : 0.f;
    }
}

extern "C" void kernel_launch(void* const* d_in, const int* in_sizes, int n_in,
                              void* d_out, int out_size, void* d_ws, size_t ws_size,
                              hipStream_t stream) {
    const int*   nodes     = (const int*)d_in[0];
    const int*   neigh_idx = (const int*)d_in[1];
    const float* features  = (const float*)d_in[2];
    const float* W_stc     = (const float*)d_in[3];
    const float* W_det     = (const float*)d_in[4];
    float* out = (float*)d_out;

    unsigned short* Bsw = (unsigned short*)d_ws;   // 768*128 bf16 = 192 KB

    prep_B<<<272, 256, 0, stream>>>(W_stc, W_det, Bsw);
    fused<<<BATCH / 16, 256, 0, stream>>>(nodes, neigh_idx, features, Bsw, out);
}